// Round 9
// baseline (289.401 us; speedup 1.0000x reference)
//
#include <hip/hip_runtime.h>

// PointNetSaModule fused — f32 in/out, f16 MFMA compute.
// R15 = R14 body (best headline 212.9, main 90us: f32 direct gather, swapped
// L0/L1, u32-pair LDS transpose, packed stores) + LDS diet to EXACTLY 40,960B
// -> 4 blocks/CU (was 3 at 47.6KB). Occupancy is the one lever never tested
// at constant per-point work (R11 confounded it with +50% DS/pt).
//   - X and W1/W2 lose padding; XOR swizzle c ^= (row&7)<<2 on u32 columns.
//     Bijective, pair-preserving (mask has no bits 0-1), b64/b128 alignment
//     kept, bank-conflict-minimal (8 groups x disjoint 4-bank sets = 8-cy
//     b128 floor, same as padded). X 18.4->16.4KB, W 27.6->24.6KB.
//   - t1/t2 biases in REGISTERS from per-lane global reads at setup; t2
//     deferred past the K-max select (max+const commutes) -> 2 regs not 8.
//   - s1/s2 scale staging dropped (inline recompute, R11-validated).
//   - PK2 cvt_pkrtz packing (R13-validated numerics, -32 VALU/iter).
// Spill canary: VGPR=128 + FETCH jump => revert to (256,3).

#define NGRP_    8192         // groups of 8 points (B*h*w/8)
#define OUTHALF_ 8388608      // elements: second output copy offset
#define EPS_     1e-5f
#define GRID_    1024         // 4 blocks/CU x 256 CUs, 8 iters exact

typedef _Float16 h8    __attribute__((ext_vector_type(8)));
typedef float    f32x4 __attribute__((ext_vector_type(4)));
typedef unsigned u32x2 __attribute__((ext_vector_type(2)));

// relu + pack two f32 -> one u32 of 2 f16 (single v_cvt_pkrtz_f16_f32)
#define PK2(lo, hi) __builtin_bit_cast(unsigned,                               \
    __builtin_amdgcn_cvt_pkrtz(fmaxf((lo), 0.f), fmaxf((hi), 0.f)))

__global__ __launch_bounds__(256, 4) void pnsa_main(
    const float* __restrict__ xyz,    // (B,HW,3) f32
    const float* __restrict__ pts,    // (B,HW,64) f32
    const float* __restrict__ xyzs,   // (B,NPT,3) f32
    const int*   __restrict__ nidx,   // (B,NPT*16)
    const float* __restrict__ vmask,  // (B,NPT,16) f32
    const float* __restrict__ w0, const float* __restrict__ b0,
    const float* __restrict__ g0, const float* __restrict__ be0,
    const float* __restrict__ m0, const float* __restrict__ v0,
    const float* __restrict__ w1, const float* __restrict__ b1,
    const float* __restrict__ g1, const float* __restrict__ be1,
    const float* __restrict__ m1, const float* __restrict__ v1,
    const float* __restrict__ w2, const float* __restrict__ b2,
    const float* __restrict__ g2, const float* __restrict__ be2,
    const float* __restrict__ m2, const float* __restrict__ v2,
    float*       __restrict__ out)
{
    // LDS: 8192 + 16384 + 16384 = 40,960B exactly -> 4 blocks/CU
    __shared__ __align__(16) _Float16 ldsW1[64 * 64];        // W1'[n][k swz]
    __shared__ __align__(16) _Float16 ldsW2[128 * 64];       // W2'[n][k swz]
    __shared__ __align__(16) unsigned ldsX[4][2][16 * 32];   // X'[nb][ch/2 swz]

    const int tid  = threadIdx.x;
    const int wave = tid >> 6;
    const int lane = tid & 63;
    const int l15  = lane & 15;
    const int quad = lane >> 4;
    const int m    = (l15 & 7) << 2;          // XOR swizzle mask (u32 units)
    const int c0   = (quad * 4) ^ m;          // swizzled u32 col, k-chunk 0
    const int c1   = (16 + quad * 4) ^ m;     // swizzled u32 col, k-chunk 1

    unsigned* XA = &ldsX[wave][0][0];
    unsigned* XB = &ldsX[wave][1][0];

    // ---- fold W1'/W2' (BN scale inline) into swizzled LDS ----
    for (int idx = tid; idx < 64 * 64; idx += 256) {     // w1[k][n] -> W1'[n][k]
        const int k = idx >> 6, n = idx & 63;
        const float s = g1[n] * rsqrtf(v1[n] + EPS_);
        const int c = (k >> 1) ^ ((n & 7) << 2);
        ldsW1[n * 64 + (c << 1) + (k & 1)] = (_Float16)(w1[idx] * s);
    }
    for (int idx = tid; idx < 64 * 128; idx += 256) {    // w2[k][n] -> W2'[n][k]
        const int k = idx >> 7, n = idx & 127;
        const float s = g2[n] * rsqrtf(v2[n] + EPS_);
        const int c = (k >> 1) ^ ((n & 7) << 2);
        ldsW2[n * 64 + (c << 1) + (k & 1)] = (_Float16)(w2[idx] * s);
    }

    // ---- t1 (acc-init bias, ch = 16nt+4q+r) and t2 (deferred) in regs ----
    f32x4 t1v[4];
#pragma unroll
    for (int nt = 0; nt < 4; ++nt) {
        const int ch = nt * 16 + quad * 4;
        const f32x4 gv  = *(const f32x4*)(g1 + ch);
        const f32x4 vv  = *(const f32x4*)(v1 + ch);
        const f32x4 bv  = *(const f32x4*)(b1 + ch);
        const f32x4 mv  = *(const f32x4*)(m1 + ch);
        const f32x4 bev = *(const f32x4*)(be1 + ch);
#pragma unroll
        for (int r = 0; r < 4; ++r) {
            const float s = gv[r] * rsqrtf(vv[r] + EPS_);
            t1v[nt][r] = (bv[r] - mv[r]) * s + bev[r];
        }
    }
    float t2lo, t2hi;
    {
        const float sa = g2[lane] * rsqrtf(v2[lane] + EPS_);
        t2lo = (b2[lane] - m2[lane]) * sa + be2[lane];
        const float sb = g2[64 + lane] * rsqrtf(v2[64 + lane] + EPS_);
        t2hi = (b2[64 + lane] - m2[64 + lane]) * sb + be2[64 + lane];
    }

    // ---- W0 BN-folded into register frags; bias via pad channel 67 ----
    // k-order: [points 0..63, xyz_diff 64..66, BIAS 67 (=1.0), pad..95]
    // Frag map (A==B on gfx950): lane holds [ch=nt*16+l15][k=kk*32+quad*8+j]
    h8 b0f[4][3];
#pragma unroll
    for (int nt = 0; nt < 4; ++nt) {
        const int ch = nt * 16 + l15;
        const float s = g0[ch] * rsqrtf(v0[ch] + EPS_);
        const float t0 = (b0[ch] - m0[ch]) * s + be0[ch];
#pragma unroll
        for (int kk = 0; kk < 3; ++kk) {
            h8 f;
#pragma unroll
            for (int j = 0; j < 8; ++j) {
                const int k = kk * 32 + quad * 8 + j;
                float wv = 0.f;
                if (k < 64)       wv = w0[(3 + k) * 64 + ch] * s;
                else if (k < 67)  wv = w0[(k - 64) * 64 + ch] * s;
                else if (k == 67) wv = t0;                 // bias via 1.0 channel
                f[j] = (_Float16)wv;
            }
            b0f[nt][kk] = f;
        }
    }
    __syncthreads();

    // ---- main loop: 8 points per block iteration (2 per wave) ----
    const int g0i = blockIdx.x;
    const int pA0 = (g0i << 3) + (wave << 1);
    int nbA = nidx[(pA0 << 4) + l15];
    int nbB = nidx[((pA0 + 1) << 4) + l15];

    for (int grp = g0i; grp < NGRP_; grp += GRID_) {
        const int pA = (grp << 3) + (wave << 1);
        const int pB = pA + 1;
        const int gn = (grp + GRID_ < NGRP_) ? grp + GRID_ : grp;
        const int pAn = (gn << 3) + (wave << 1);

        // gather loads for both points (issue early), f32 direct
        const size_t rowA = (size_t)(((pA >> 14) << 16) + nbA);
        const size_t rowB = (size_t)(((pB >> 14) << 16) + nbB);
        h8 qA0, qA1, qB0, qB1;
        {
            const float* pwA = pts + (rowA << 6);
            const float* pwB = pts + (rowB << 6);
            f32x4 r0, r1, r2, r3;
            r0 = *(const f32x4*)(pwA + quad * 8);      r1 = *(const f32x4*)(pwA + quad * 8 + 4);
            r2 = *(const f32x4*)(pwA + 32 + quad * 8); r3 = *(const f32x4*)(pwA + 32 + quad * 8 + 4);
#pragma unroll
            for (int j = 0; j < 4; ++j) { qA0[j]=(_Float16)r0[j]; qA0[4+j]=(_Float16)r1[j];
                                          qA1[j]=(_Float16)r2[j]; qA1[4+j]=(_Float16)r3[j]; }
            r0 = *(const f32x4*)(pwB + quad * 8);      r1 = *(const f32x4*)(pwB + quad * 8 + 4);
            r2 = *(const f32x4*)(pwB + 32 + quad * 8); r3 = *(const f32x4*)(pwB + 32 + quad * 8 + 4);
#pragma unroll
            for (int j = 0; j < 4; ++j) { qB0[j]=(_Float16)r0[j]; qB0[4+j]=(_Float16)r1[j];
                                          qB1[j]=(_Float16)r2[j]; qB1[4+j]=(_Float16)r3[j]; }
        }
        const float mkA = vmask[(pA << 4) + l15];
        const float mkB = vmask[(pB << 4) + l15];
        const float* xgA = xyz + rowA * 3;
        const float* xgB = xyz + rowB * 3;
        const float xgA0 = xgA[0], xgA1 = xgA[1], xgA2 = xgA[2];
        const float xgB0 = xgB[0], xgB1 = xgB[1], xgB2 = xgB[2];
        const float* xsA = xyzs + (size_t)pA * 3;
        const float* xsB = xyzs + (size_t)pB * 3;
        const float xsA0 = xsA[0], xsA1 = xsA[1], xsA2 = xsA[2];
        const float xsB0 = xsB[0], xsB1 = xsB[1], xsB2 = xsB[2];

        // prefetch next iteration's neighbor indices
        const int nbAn = nidx[(pAn << 4) + l15];
        const int nbBn = nidx[((pAn + 1) << 4) + l15];

        if (mkA == 0.0f) { qA0 = (h8)(_Float16)0.f; qA1 = (h8)(_Float16)0.f; }
        if (mkB == 0.0f) { qB0 = (h8)(_Float16)0.f; qB1 = (h8)(_Float16)0.f; }
        h8 aA2 = (h8)(_Float16)0.f, aB2 = (h8)(_Float16)0.f;
        if (quad == 0) {
            aA2[0] = (_Float16)(xgA0 * mkA - xsA0);
            aA2[1] = (_Float16)(xgA1 * mkA - xsA1);
            aA2[2] = (_Float16)(xgA2 * mkA - xsA2);
            aA2[3] = (_Float16)1.0f;               // bias channel
            aB2[0] = (_Float16)(xgB0 * mkB - xsB0);
            aB2[1] = (_Float16)(xgB1 * mkB - xsB1);
            aB2[2] = (_Float16)(xgB2 * mkB - xsB2);
            aB2[3] = (_Float16)1.0f;
        }

        // ---- layer 0 SWAPPED: D = W0'' X^T -> acc[r] = X1[16nt+4q+r][nb=l15]
#pragma unroll
        for (int nt = 0; nt < 4; ++nt) {
            f32x4 aA = {0.f,0.f,0.f,0.f}, aB = {0.f,0.f,0.f,0.f};
            aA = __builtin_amdgcn_mfma_f32_16x16x32_f16(b0f[nt][0], qA0, aA, 0, 0, 0);
            aA = __builtin_amdgcn_mfma_f32_16x16x32_f16(b0f[nt][1], qA1, aA, 0, 0, 0);
            aA = __builtin_amdgcn_mfma_f32_16x16x32_f16(b0f[nt][2], aA2, aA, 0, 0, 0);
            aB = __builtin_amdgcn_mfma_f32_16x16x32_f16(b0f[nt][0], qB0, aB, 0, 0, 0);
            aB = __builtin_amdgcn_mfma_f32_16x16x32_f16(b0f[nt][1], qB1, aB, 0, 0, 0);
            aB = __builtin_amdgcn_mfma_f32_16x16x32_f16(b0f[nt][2], aB2, aB, 0, 0, 0);
            u32x2 pkA = {PK2(aA[0], aA[1]), PK2(aA[2], aA[3])};
            u32x2 pkB = {PK2(aB[0], aB[1]), PK2(aB[2], aB[3])};
            const int cw = (nt * 8 + quad * 2) ^ m;
            *(u32x2*)(XA + l15 * 32 + cw) = pkA;
            *(u32x2*)(XB + l15 * 32 + cw) = pkB;
        }

        // ---- layer 1 SWAPPED (reads precede overwrites; DS in-order/wave) ----
        h8 xA0 = *(const h8*)(XA + l15 * 32 + c0);
        h8 xA1 = *(const h8*)(XA + l15 * 32 + c1);
        h8 xB0 = *(const h8*)(XB + l15 * 32 + c0);
        h8 xB1 = *(const h8*)(XB + l15 * 32 + c1);
#pragma unroll 2
        for (int nt = 0; nt < 4; ++nt) {
            const _Float16* wrow = ldsW1 + (nt * 16 + l15) * 64;
            h8 wa = *(const h8*)(wrow + (c0 << 1));
            h8 wb = *(const h8*)(wrow + (c1 << 1));
            f32x4 aA = t1v[nt], aB = t1v[nt];   // bias in acc (ch = 16nt+4q+r)
            aA = __builtin_amdgcn_mfma_f32_16x16x32_f16(wa, xA0, aA, 0, 0, 0);
            aA = __builtin_amdgcn_mfma_f32_16x16x32_f16(wb, xA1, aA, 0, 0, 0);
            aB = __builtin_amdgcn_mfma_f32_16x16x32_f16(wa, xB0, aB, 0, 0, 0);
            aB = __builtin_amdgcn_mfma_f32_16x16x32_f16(wb, xB1, aB, 0, 0, 0);
            u32x2 pkA = {PK2(aA[0], aA[1]), PK2(aA[2], aA[3])};
            u32x2 pkB = {PK2(aB[0], aB[1]), PK2(aB[2], aB[3])};
            const int cw = (nt * 8 + quad * 2) ^ m;
            *(u32x2*)(XA + l15 * 32 + cw) = pkA;
            *(u32x2*)(XB + l15 * 32 + cw) = pkB;
        }

        // ---- layer 2 NORMAL: X frags as A-operand + K-maxpool + packed stores
        h8 yA0 = *(const h8*)(XA + l15 * 32 + c0);
        h8 yA1 = *(const h8*)(XA + l15 * 32 + c1);
        h8 yB0 = *(const h8*)(XB + l15 * 32 + c0);
        h8 yB1 = *(const h8*)(XB + l15 * 32 + c1);
        float sAlo = 0.f, sAhi = 0.f, sBlo = 0.f, sBhi = 0.f;
#pragma unroll 2
        for (int nt = 0; nt < 8; ++nt) {
            const _Float16* wrow = ldsW2 + (nt * 16 + l15) * 64;
            h8 wa = *(const h8*)(wrow + (c0 << 1));
            h8 wb = *(const h8*)(wrow + (c1 << 1));
            f32x4 aA = {0.f,0.f,0.f,0.f}, aB = {0.f,0.f,0.f,0.f};
            aA = __builtin_amdgcn_mfma_f32_16x16x32_f16(yA0, wa, aA, 0, 0, 0);
            aA = __builtin_amdgcn_mfma_f32_16x16x32_f16(yA1, wb, aA, 0, 0, 0);
            aB = __builtin_amdgcn_mfma_f32_16x16x32_f16(yB0, wa, aB, 0, 0, 0);
            aB = __builtin_amdgcn_mfma_f32_16x16x32_f16(yB1, wb, aB, 0, 0, 0);
            float vA = fmaxf(fmaxf(aA[0], aA[1]), fmaxf(aA[2], aA[3]));
            float vB = fmaxf(fmaxf(aB[0], aB[1]), fmaxf(aB[2], aB[3]));
            vA = fmaxf(vA, __shfl_xor(vA, 16, 64));
            vA = fmaxf(vA, __shfl_xor(vA, 32, 64));       // now quad-uniform
            vB = fmaxf(vB, __shfl_xor(vB, 16, 64));
            vB = fmaxf(vB, __shfl_xor(vB, 32, 64));
            // select this lane's channel (ch = quad*16+l15 or +64):
            if (nt < 4) {
                sAlo = (quad == nt) ? vA : sAlo;
                sBlo = (quad == nt) ? vB : sBlo;
            } else {
                sAhi = (quad == nt - 4) ? vA : sAhi;
                sBhi = (quad == nt - 4) ? vB : sBhi;
            }
        }
        // deferred bias + relu (max+const commutes; relu(max)=max(relu))
        sAlo = fmaxf(sAlo + t2lo, 0.f);  sAhi = fmaxf(sAhi + t2hi, 0.f);
        sBlo = fmaxf(sBlo + t2lo, 0.f);  sBhi = fmaxf(sBhi + t2hi, 0.f);
        // all 64 lanes store; lane = quad*16+l15 -> 256B coalesced stores
        {
            float* obA = out + ((size_t)pA << 7);
            float* obB = out + ((size_t)pB << 7);
            obA[lane]                  = sAlo;
            obA[64 + lane]             = sAhi;
            obA[OUTHALF_ + lane]       = sAlo;
            obA[OUTHALF_ + 64 + lane]  = sAhi;
            obB[lane]                  = sBlo;
            obB[64 + lane]             = sBhi;
            obB[OUTHALF_ + lane]       = sBlo;
            obB[OUTHALF_ + 64 + lane]  = sBhi;
        }

        nbA = nbAn; nbB = nbBn;
    }
}

extern "C" void kernel_launch(void* const* d_in, const int* in_sizes, int n_in,
                              void* d_out, int out_size, void* d_ws, size_t ws_size,
                              hipStream_t stream) {
    const float* xyz   = (const float*)d_in[0];
    const float* pts   = (const float*)d_in[1];
    const float* xyzs  = (const float*)d_in[2];
    const int*   nidx  = (const int*)d_in[3];
    const float* vmask = (const float*)d_in[4];
    const float *w0 = (const float*)d_in[5],  *b0 = (const float*)d_in[6],
                *g0 = (const float*)d_in[7],  *be0 = (const float*)d_in[8],
                *m0 = (const float*)d_in[9],  *v0 = (const float*)d_in[10];
    const float *w1 = (const float*)d_in[11], *b1 = (const float*)d_in[12],
                *g1 = (const float*)d_in[13], *be1 = (const float*)d_in[14],
                *m1 = (const float*)d_in[15], *v1 = (const float*)d_in[16];
    const float *w2 = (const float*)d_in[17], *b2 = (const float*)d_in[18],
                *g2 = (const float*)d_in[19], *be2 = (const float*)d_in[20],
                *m2 = (const float*)d_in[21], *v2 = (const float*)d_in[22];
    float* outp = (float*)d_out;

    pnsa_main<<<dim3(GRID_), dim3(256), 0, stream>>>(
        xyz, pts, xyzs, nidx, vmask,
        w0, b0, g0, be0, m0, v0,
        w1, b1, g1, be1, m1, v1,
        w2, b2, g2, be2, m2, v2, outp);
}

// Round 10
// 227.921 us; speedup vs baseline: 1.2697x; 1.2697x over previous
//
#include <hip/hip_runtime.h>

// PointNetSaModule fused — f32 in/out, f16 MFMA compute.
// R16 = R15's validated pieces at the PROVEN register regime (256,3)/768.
// R15 post-mortem: (256,4) unified-128 cap spilled AGAIN (R7 repeat): arch
// VGPR 64 + AGPR = cap, FETCH 141->304MB, WRITE 65->195MB scratch, 164us.
// (256,4) is permanently off the table for this body. But R15 validated:
//   - XOR-swizzled unpadded LDS: bank conflicts 7.2M -> 3.3M (DS op count
//     unchanged by spill, so drop is layout-attributable). 40,960B total.
//   - t1/t2 biases in registers (-~12 DS reads/wave-iter), PK2 cvt_pkrtz
//     (-32 VALU/wave-iter); both numerically clean (absmax 0.015625).
// R14 vs R10 accounting: +64MB HBM cost only +5.5us -> NOT BW-bound; kernel
// is issue/latency-bound, so instruction cuts are the right residual lever.
// Config: launch_bounds(256,3), grid 768 (3 blocks/CU guaranteed; LDS 40,960
// leaves room for a 4th block if unified regs land <=128 — bonus only).

#define NGRP_    8192         // groups of 8 points (B*h*w/8)
#define OUTHALF_ 8388608      // elements: second output copy offset
#define EPS_     1e-5f
#define GRID_    768          // 3 blocks/CU x 256 CUs

typedef _Float16 h8    __attribute__((ext_vector_type(8)));
typedef float    f32x4 __attribute__((ext_vector_type(4)));
typedef unsigned u32x2 __attribute__((ext_vector_type(2)));

// relu + pack two f32 -> one u32 of 2 f16 (single v_cvt_pkrtz_f16_f32)
#define PK2(lo, hi) __builtin_bit_cast(unsigned,                               \
    __builtin_amdgcn_cvt_pkrtz(fmaxf((lo), 0.f), fmaxf((hi), 0.f)))

__global__ __launch_bounds__(256, 3) void pnsa_main(
    const float* __restrict__ xyz,    // (B,HW,3) f32
    const float* __restrict__ pts,    // (B,HW,64) f32
    const float* __restrict__ xyzs,   // (B,NPT,3) f32
    const int*   __restrict__ nidx,   // (B,NPT*16)
    const float* __restrict__ vmask,  // (B,NPT,16) f32
    const float* __restrict__ w0, const float* __restrict__ b0,
    const float* __restrict__ g0, const float* __restrict__ be0,
    const float* __restrict__ m0, const float* __restrict__ v0,
    const float* __restrict__ w1, const float* __restrict__ b1,
    const float* __restrict__ g1, const float* __restrict__ be1,
    const float* __restrict__ m1, const float* __restrict__ v1,
    const float* __restrict__ w2, const float* __restrict__ b2,
    const float* __restrict__ g2, const float* __restrict__ be2,
    const float* __restrict__ m2, const float* __restrict__ v2,
    float*       __restrict__ out)
{
    // LDS: 8192 + 16384 + 16384 = 40,960B
    __shared__ __align__(16) _Float16 ldsW1[64 * 64];        // W1'[n][k swz]
    __shared__ __align__(16) _Float16 ldsW2[128 * 64];       // W2'[n][k swz]
    __shared__ __align__(16) unsigned ldsX[4][2][16 * 32];   // X'[nb][ch/2 swz]

    const int tid  = threadIdx.x;
    const int wave = tid >> 6;
    const int lane = tid & 63;
    const int l15  = lane & 15;
    const int quad = lane >> 4;
    const int m    = (l15 & 7) << 2;          // XOR swizzle mask (u32 units)
    const int c0   = (quad * 4) ^ m;          // swizzled u32 col, k-chunk 0
    const int c1   = (16 + quad * 4) ^ m;     // swizzled u32 col, k-chunk 1

    unsigned* XA = &ldsX[wave][0][0];
    unsigned* XB = &ldsX[wave][1][0];

    // ---- fold W1'/W2' (BN scale inline) into swizzled LDS ----
    for (int idx = tid; idx < 64 * 64; idx += 256) {     // w1[k][n] -> W1'[n][k]
        const int k = idx >> 6, n = idx & 63;
        const float s = g1[n] * rsqrtf(v1[n] + EPS_);
        const int c = (k >> 1) ^ ((n & 7) << 2);
        ldsW1[n * 64 + (c << 1) + (k & 1)] = (_Float16)(w1[idx] * s);
    }
    for (int idx = tid; idx < 64 * 128; idx += 256) {    // w2[k][n] -> W2'[n][k]
        const int k = idx >> 7, n = idx & 127;
        const float s = g2[n] * rsqrtf(v2[n] + EPS_);
        const int c = (k >> 1) ^ ((n & 7) << 2);
        ldsW2[n * 64 + (c << 1) + (k & 1)] = (_Float16)(w2[idx] * s);
    }

    // ---- t1 (acc-init bias, ch = 16nt+4q+r) and t2 (deferred) in regs ----
    f32x4 t1v[4];
#pragma unroll
    for (int nt = 0; nt < 4; ++nt) {
        const int ch = nt * 16 + quad * 4;
        const f32x4 gv  = *(const f32x4*)(g1 + ch);
        const f32x4 vv  = *(const f32x4*)(v1 + ch);
        const f32x4 bv  = *(const f32x4*)(b1 + ch);
        const f32x4 mv  = *(const f32x4*)(m1 + ch);
        const f32x4 bev = *(const f32x4*)(be1 + ch);
#pragma unroll
        for (int r = 0; r < 4; ++r) {
            const float s = gv[r] * rsqrtf(vv[r] + EPS_);
            t1v[nt][r] = (bv[r] - mv[r]) * s + bev[r];
        }
    }
    float t2lo, t2hi;
    {
        const float sa = g2[lane] * rsqrtf(v2[lane] + EPS_);
        t2lo = (b2[lane] - m2[lane]) * sa + be2[lane];
        const float sb = g2[64 + lane] * rsqrtf(v2[64 + lane] + EPS_);
        t2hi = (b2[64 + lane] - m2[64 + lane]) * sb + be2[64 + lane];
    }

    // ---- W0 BN-folded into register frags; bias via pad channel 67 ----
    // k-order: [points 0..63, xyz_diff 64..66, BIAS 67 (=1.0), pad..95]
    // Frag map (A==B on gfx950): lane holds [ch=nt*16+l15][k=kk*32+quad*8+j]
    h8 b0f[4][3];
#pragma unroll
    for (int nt = 0; nt < 4; ++nt) {
        const int ch = nt * 16 + l15;
        const float s = g0[ch] * rsqrtf(v0[ch] + EPS_);
        const float t0 = (b0[ch] - m0[ch]) * s + be0[ch];
#pragma unroll
        for (int kk = 0; kk < 3; ++kk) {
            h8 f;
#pragma unroll
            for (int j = 0; j < 8; ++j) {
                const int k = kk * 32 + quad * 8 + j;
                float wv = 0.f;
                if (k < 64)       wv = w0[(3 + k) * 64 + ch] * s;
                else if (k < 67)  wv = w0[(k - 64) * 64 + ch] * s;
                else if (k == 67) wv = t0;                 // bias via 1.0 channel
                f[j] = (_Float16)wv;
            }
            b0f[nt][kk] = f;
        }
    }
    __syncthreads();

    // ---- main loop: 8 points per block iteration (2 per wave) ----
    const int g0i = blockIdx.x;
    const int pA0 = (g0i << 3) + (wave << 1);
    int nbA = nidx[(pA0 << 4) + l15];
    int nbB = nidx[((pA0 + 1) << 4) + l15];

    for (int grp = g0i; grp < NGRP_; grp += GRID_) {
        const int pA = (grp << 3) + (wave << 1);
        const int pB = pA + 1;
        const int gn = (grp + GRID_ < NGRP_) ? grp + GRID_ : grp;
        const int pAn = (gn << 3) + (wave << 1);

        // gather loads for both points (issue early), f32 direct
        const size_t rowA = (size_t)(((pA >> 14) << 16) + nbA);
        const size_t rowB = (size_t)(((pB >> 14) << 16) + nbB);
        h8 qA0, qA1, qB0, qB1;
        {
            const float* pwA = pts + (rowA << 6);
            const float* pwB = pts + (rowB << 6);
            f32x4 r0, r1, r2, r3;
            r0 = *(const f32x4*)(pwA + quad * 8);      r1 = *(const f32x4*)(pwA + quad * 8 + 4);
            r2 = *(const f32x4*)(pwA + 32 + quad * 8); r3 = *(const f32x4*)(pwA + 32 + quad * 8 + 4);
#pragma unroll
            for (int j = 0; j < 4; ++j) { qA0[j]=(_Float16)r0[j]; qA0[4+j]=(_Float16)r1[j];
                                          qA1[j]=(_Float16)r2[j]; qA1[4+j]=(_Float16)r3[j]; }
            r0 = *(const f32x4*)(pwB + quad * 8);      r1 = *(const f32x4*)(pwB + quad * 8 + 4);
            r2 = *(const f32x4*)(pwB + 32 + quad * 8); r3 = *(const f32x4*)(pwB + 32 + quad * 8 + 4);
#pragma unroll
            for (int j = 0; j < 4; ++j) { qB0[j]=(_Float16)r0[j]; qB0[4+j]=(_Float16)r1[j];
                                          qB1[j]=(_Float16)r2[j]; qB1[4+j]=(_Float16)r3[j]; }
        }
        const float mkA = vmask[(pA << 4) + l15];
        const float mkB = vmask[(pB << 4) + l15];
        const float* xgA = xyz + rowA * 3;
        const float* xgB = xyz + rowB * 3;
        const float xgA0 = xgA[0], xgA1 = xgA[1], xgA2 = xgA[2];
        const float xgB0 = xgB[0], xgB1 = xgB[1], xgB2 = xgB[2];
        const float* xsA = xyzs + (size_t)pA * 3;
        const float* xsB = xyzs + (size_t)pB * 3;
        const float xsA0 = xsA[0], xsA1 = xsA[1], xsA2 = xsA[2];
        const float xsB0 = xsB[0], xsB1 = xsB[1], xsB2 = xsB[2];

        // prefetch next iteration's neighbor indices
        const int nbAn = nidx[(pAn << 4) + l15];
        const int nbBn = nidx[((pAn + 1) << 4) + l15];

        if (mkA == 0.0f) { qA0 = (h8)(_Float16)0.f; qA1 = (h8)(_Float16)0.f; }
        if (mkB == 0.0f) { qB0 = (h8)(_Float16)0.f; qB1 = (h8)(_Float16)0.f; }
        h8 aA2 = (h8)(_Float16)0.f, aB2 = (h8)(_Float16)0.f;
        if (quad == 0) {
            aA2[0] = (_Float16)(xgA0 * mkA - xsA0);
            aA2[1] = (_Float16)(xgA1 * mkA - xsA1);
            aA2[2] = (_Float16)(xgA2 * mkA - xsA2);
            aA2[3] = (_Float16)1.0f;               // bias channel
            aB2[0] = (_Float16)(xgB0 * mkB - xsB0);
            aB2[1] = (_Float16)(xgB1 * mkB - xsB1);
            aB2[2] = (_Float16)(xgB2 * mkB - xsB2);
            aB2[3] = (_Float16)1.0f;
        }

        // ---- layer 0 SWAPPED: D = W0'' X^T -> acc[r] = X1[16nt+4q+r][nb=l15]
#pragma unroll
        for (int nt = 0; nt < 4; ++nt) {
            f32x4 aA = {0.f,0.f,0.f,0.f}, aB = {0.f,0.f,0.f,0.f};
            aA = __builtin_amdgcn_mfma_f32_16x16x32_f16(b0f[nt][0], qA0, aA, 0, 0, 0);
            aA = __builtin_amdgcn_mfma_f32_16x16x32_f16(b0f[nt][1], qA1, aA, 0, 0, 0);
            aA = __builtin_amdgcn_mfma_f32_16x16x32_f16(b0f[nt][2], aA2, aA, 0, 0, 0);
            aB = __builtin_amdgcn_mfma_f32_16x16x32_f16(b0f[nt][0], qB0, aB, 0, 0, 0);
            aB = __builtin_amdgcn_mfma_f32_16x16x32_f16(b0f[nt][1], qB1, aB, 0, 0, 0);
            aB = __builtin_amdgcn_mfma_f32_16x16x32_f16(b0f[nt][2], aB2, aB, 0, 0, 0);
            u32x2 pkA = {PK2(aA[0], aA[1]), PK2(aA[2], aA[3])};
            u32x2 pkB = {PK2(aB[0], aB[1]), PK2(aB[2], aB[3])};
            const int cw = (nt * 8 + quad * 2) ^ m;
            *(u32x2*)(XA + l15 * 32 + cw) = pkA;
            *(u32x2*)(XB + l15 * 32 + cw) = pkB;
        }

        // ---- layer 1 SWAPPED (reads precede overwrites; DS in-order/wave) ----
        h8 xA0 = *(const h8*)(XA + l15 * 32 + c0);
        h8 xA1 = *(const h8*)(XA + l15 * 32 + c1);
        h8 xB0 = *(const h8*)(XB + l15 * 32 + c0);
        h8 xB1 = *(const h8*)(XB + l15 * 32 + c1);
#pragma unroll 2
        for (int nt = 0; nt < 4; ++nt) {
            const _Float16* wrow = ldsW1 + (nt * 16 + l15) * 64;
            h8 wa = *(const h8*)(wrow + (c0 << 1));
            h8 wb = *(const h8*)(wrow + (c1 << 1));
            f32x4 aA = t1v[nt], aB = t1v[nt];   // bias in acc (ch = 16nt+4q+r)
            aA = __builtin_amdgcn_mfma_f32_16x16x32_f16(wa, xA0, aA, 0, 0, 0);
            aA = __builtin_amdgcn_mfma_f32_16x16x32_f16(wb, xA1, aA, 0, 0, 0);
            aB = __builtin_amdgcn_mfma_f32_16x16x32_f16(wa, xB0, aB, 0, 0, 0);
            aB = __builtin_amdgcn_mfma_f32_16x16x32_f16(wb, xB1, aB, 0, 0, 0);
            u32x2 pkA = {PK2(aA[0], aA[1]), PK2(aA[2], aA[3])};
            u32x2 pkB = {PK2(aB[0], aB[1]), PK2(aB[2], aB[3])};
            const int cw = (nt * 8 + quad * 2) ^ m;
            *(u32x2*)(XA + l15 * 32 + cw) = pkA;
            *(u32x2*)(XB + l15 * 32 + cw) = pkB;
        }

        // ---- layer 2 NORMAL: X frags as A-operand + K-maxpool + packed stores
        h8 yA0 = *(const h8*)(XA + l15 * 32 + c0);
        h8 yA1 = *(const h8*)(XA + l15 * 32 + c1);
        h8 yB0 = *(const h8*)(XB + l15 * 32 + c0);
        h8 yB1 = *(const h8*)(XB + l15 * 32 + c1);
        float sAlo = 0.f, sAhi = 0.f, sBlo = 0.f, sBhi = 0.f;
#pragma unroll 2
        for (int nt = 0; nt < 8; ++nt) {
            const _Float16* wrow = ldsW2 + (nt * 16 + l15) * 64;
            h8 wa = *(const h8*)(wrow + (c0 << 1));
            h8 wb = *(const h8*)(wrow + (c1 << 1));
            f32x4 aA = {0.f,0.f,0.f,0.f}, aB = {0.f,0.f,0.f,0.f};
            aA = __builtin_amdgcn_mfma_f32_16x16x32_f16(yA0, wa, aA, 0, 0, 0);
            aA = __builtin_amdgcn_mfma_f32_16x16x32_f16(yA1, wb, aA, 0, 0, 0);
            aB = __builtin_amdgcn_mfma_f32_16x16x32_f16(yB0, wa, aB, 0, 0, 0);
            aB = __builtin_amdgcn_mfma_f32_16x16x32_f16(yB1, wb, aB, 0, 0, 0);
            float vA = fmaxf(fmaxf(aA[0], aA[1]), fmaxf(aA[2], aA[3]));
            float vB = fmaxf(fmaxf(aB[0], aB[1]), fmaxf(aB[2], aB[3]));
            vA = fmaxf(vA, __shfl_xor(vA, 16, 64));
            vA = fmaxf(vA, __shfl_xor(vA, 32, 64));       // now quad-uniform
            vB = fmaxf(vB, __shfl_xor(vB, 16, 64));
            vB = fmaxf(vB, __shfl_xor(vB, 32, 64));
            // select this lane's channel (ch = quad*16+l15 or +64):
            if (nt < 4) {
                sAlo = (quad == nt) ? vA : sAlo;
                sBlo = (quad == nt) ? vB : sBlo;
            } else {
                sAhi = (quad == nt - 4) ? vA : sAhi;
                sBhi = (quad == nt - 4) ? vB : sBhi;
            }
        }
        // deferred bias + relu (max+const commutes; relu(max)=max(relu))
        sAlo = fmaxf(sAlo + t2lo, 0.f);  sAhi = fmaxf(sAhi + t2hi, 0.f);
        sBlo = fmaxf(sBlo + t2lo, 0.f);  sBhi = fmaxf(sBhi + t2hi, 0.f);
        // all 64 lanes store; lane = quad*16+l15 -> 256B coalesced stores
        {
            float* obA = out + ((size_t)pA << 7);
            float* obB = out + ((size_t)pB << 7);
            obA[lane]                  = sAlo;
            obA[64 + lane]             = sAhi;
            obA[OUTHALF_ + lane]       = sAlo;
            obA[OUTHALF_ + 64 + lane]  = sAhi;
            obB[lane]                  = sBlo;
            obB[64 + lane]             = sBhi;
            obB[OUTHALF_ + lane]       = sBlo;
            obB[OUTHALF_ + 64 + lane]  = sBhi;
        }

        nbA = nbAn; nbB = nbBn;
    }
}

extern "C" void kernel_launch(void* const* d_in, const int* in_sizes, int n_in,
                              void* d_out, int out_size, void* d_ws, size_t ws_size,
                              hipStream_t stream) {
    const float* xyz   = (const float*)d_in[0];
    const float* pts   = (const float*)d_in[1];
    const float* xyzs  = (const float*)d_in[2];
    const int*   nidx  = (const int*)d_in[3];
    const float* vmask = (const float*)d_in[4];
    const float *w0 = (const float*)d_in[5],  *b0 = (const float*)d_in[6],
                *g0 = (const float*)d_in[7],  *be0 = (const float*)d_in[8],
                *m0 = (const float*)d_in[9],  *v0 = (const float*)d_in[10];
    const float *w1 = (const float*)d_in[11], *b1 = (const float*)d_in[12],
                *g1 = (const float*)d_in[13], *be1 = (const float*)d_in[14],
                *m1 = (const float*)d_in[15], *v1 = (const float*)d_in[16];
    const float *w2 = (const float*)d_in[17], *b2 = (const float*)d_in[18],
                *g2 = (const float*)d_in[19], *be2 = (const float*)d_in[20],
                *m2 = (const float*)d_in[21], *v2 = (const float*)d_in[22];
    float* outp = (float*)d_out;

    pnsa_main<<<dim3(GRID_), dim3(256), 0, stream>>>(
        xyz, pts, xyzs, nidx, vmask,
        w0, b0, g0, be0, m0, v0,
        w1, b1, g1, be1, m1, v1,
        w2, b2, g2, be2, m2, v2, outp);
}

// Round 11
// 213.801 us; speedup vs baseline: 1.3536x; 1.0660x over previous
//
#include <hip/hip_runtime.h>

// PointNetSaModule fused — f32 in/out, f16 MFMA compute.
// R17 = R14 (best: headline 212.9, main 90us) + ONLY the zero-register-cost
// pieces of R16:
//   - swizzled unpadded X/W LDS (R16-validated: conflicts 7.2M->2.98M, clean
//     numerics). Costs 3 precomputed lane-constant VGPRs, nothing per-iter.
//   - PK2 cvt_pkrtz packing (-32 VALU/iter, fewer live temps; validated 3x).
// t1/t2 BACK IN LDS exactly as R14 (R16 post-mortem: t1v/t2 registers (+18)
// tipped the unified-reg cliff -> scratch spill, WRITE 65->104MB, 120us.
// This body tolerates ~zero added persistent registers; 6 small DS reads/iter
// are cheaper than 18 regs at this pressure).
// Config: (256,3)/768, f32 direct gather, packed stores — all R14 verbatim.
// Success criterion: FETCH ~141MB / WRITE ~65.5MB (no-spill signature).

#define NGRP_    8192         // groups of 8 points (B*h*w/8)
#define OUTHALF_ 8388608      // elements: second output copy offset
#define EPS_     1e-5f
#define GRID_    768          // 3 blocks/CU x 256 CUs

typedef _Float16 h8    __attribute__((ext_vector_type(8)));
typedef float    f32x4 __attribute__((ext_vector_type(4)));
typedef unsigned u32x2 __attribute__((ext_vector_type(2)));

// relu + pack two f32 -> one u32 of 2 f16 (single v_cvt_pkrtz_f16_f32)
#define PK2(lo, hi) __builtin_bit_cast(unsigned,                               \
    __builtin_amdgcn_cvt_pkrtz(fmaxf((lo), 0.f), fmaxf((hi), 0.f)))

__global__ __launch_bounds__(256, 3) void pnsa_main(
    const float* __restrict__ xyz,    // (B,HW,3) f32
    const float* __restrict__ pts,    // (B,HW,64) f32
    const float* __restrict__ xyzs,   // (B,NPT,3) f32
    const int*   __restrict__ nidx,   // (B,NPT*16)
    const float* __restrict__ vmask,  // (B,NPT,16) f32
    const float* __restrict__ w0, const float* __restrict__ b0,
    const float* __restrict__ g0, const float* __restrict__ be0,
    const float* __restrict__ m0, const float* __restrict__ v0,
    const float* __restrict__ w1, const float* __restrict__ b1,
    const float* __restrict__ g1, const float* __restrict__ be1,
    const float* __restrict__ m1, const float* __restrict__ v1,
    const float* __restrict__ w2, const float* __restrict__ b2,
    const float* __restrict__ g2, const float* __restrict__ be2,
    const float* __restrict__ m2, const float* __restrict__ v2,
    float*       __restrict__ out)
{
    // LDS: 8192 + 16384 + 16384 + 512 + 1024 = 42,496B -> 3 blocks/CU
    __shared__ __align__(16) _Float16 ldsW1[64 * 64];        // W1'[n][k swz]
    __shared__ __align__(16) _Float16 ldsW2[128 * 64];       // W2'[n][k swz]
    __shared__ __align__(16) unsigned ldsX[4][2][16 * 32];   // X'[nb][ch/2 swz]
    __shared__ __align__(16) float    s1sh[64], t1sh[64];
    __shared__ __align__(16) float    s2sh[128], t2sh[128];

    const int tid  = threadIdx.x;
    const int wave = tid >> 6;
    const int lane = tid & 63;
    const int l15  = lane & 15;
    const int quad = lane >> 4;
    const int m    = (l15 & 7) << 2;          // XOR swizzle mask (u32 units)
    const int c0   = (quad * 4) ^ m;          // swizzled u32 col, k-chunk 0
    const int c1   = (16 + quad * 4) ^ m;     // swizzled u32 col, k-chunk 1

    unsigned* XA = &ldsX[wave][0][0];
    unsigned* XB = &ldsX[wave][1][0];

    // ---- stage BN scales + shifted biases ----
    if (tid < 64) {
        const float s = g1[tid] * rsqrtf(v1[tid] + EPS_);
        s1sh[tid] = s;
        t1sh[tid] = (b1[tid] - m1[tid]) * s + be1[tid];
    }
    if (tid < 128) {
        const float s = g2[tid] * rsqrtf(v2[tid] + EPS_);
        s2sh[tid] = s;
        t2sh[tid] = (b2[tid] - m2[tid]) * s + be2[tid];
    }
    __syncthreads();
    // ---- fold W1'/W2' into swizzled LDS ----
    for (int idx = tid; idx < 64 * 64; idx += 256) {     // w1[k][n] -> W1'[n][k]
        const int k = idx >> 6, n = idx & 63;
        const int c = (k >> 1) ^ ((n & 7) << 2);
        ldsW1[n * 64 + (c << 1) + (k & 1)] = (_Float16)(w1[idx] * s1sh[n]);
    }
    for (int idx = tid; idx < 64 * 128; idx += 256) {    // w2[k][n] -> W2'[n][k]
        const int k = idx >> 7, n = idx & 127;
        const int c = (k >> 1) ^ ((n & 7) << 2);
        ldsW2[n * 64 + (c << 1) + (k & 1)] = (_Float16)(w2[idx] * s2sh[n]);
    }
    __syncthreads();

    // ---- W0 BN-folded into register frags; bias via pad channel 67 ----
    // k-order: [points 0..63, xyz_diff 64..66, BIAS 67 (=1.0), pad..95]
    // Frag map (A==B on gfx950): lane holds [ch=nt*16+l15][k=kk*32+quad*8+j]
    h8 b0f[4][3];
#pragma unroll
    for (int nt = 0; nt < 4; ++nt) {
        const int ch = nt * 16 + l15;
        const float s = g0[ch] * rsqrtf(v0[ch] + EPS_);
        const float t0 = (b0[ch] - m0[ch]) * s + be0[ch];
#pragma unroll
        for (int kk = 0; kk < 3; ++kk) {
            h8 f;
#pragma unroll
            for (int j = 0; j < 8; ++j) {
                const int k = kk * 32 + quad * 8 + j;
                float wv = 0.f;
                if (k < 64)       wv = w0[(3 + k) * 64 + ch] * s;
                else if (k < 67)  wv = w0[(k - 64) * 64 + ch] * s;
                else if (k == 67) wv = t0;                 // bias via 1.0 channel
                f[j] = (_Float16)wv;
            }
            b0f[nt][kk] = f;
        }
    }

    // ---- main loop: 8 points per block iteration (2 per wave) ----
    const int g0i = blockIdx.x;
    const int pA0 = (g0i << 3) + (wave << 1);
    int nbA = nidx[(pA0 << 4) + l15];
    int nbB = nidx[((pA0 + 1) << 4) + l15];

    for (int grp = g0i; grp < NGRP_; grp += GRID_) {
        const int pA = (grp << 3) + (wave << 1);
        const int pB = pA + 1;
        const int gn = (grp + GRID_ < NGRP_) ? grp + GRID_ : grp;
        const int pAn = (gn << 3) + (wave << 1);

        // gather loads for both points (issue early), f32 direct
        const size_t rowA = (size_t)(((pA >> 14) << 16) + nbA);
        const size_t rowB = (size_t)(((pB >> 14) << 16) + nbB);
        h8 qA0, qA1, qB0, qB1;
        {
            const float* pwA = pts + (rowA << 6);
            const float* pwB = pts + (rowB << 6);
            f32x4 r0, r1, r2, r3;
            r0 = *(const f32x4*)(pwA + quad * 8);      r1 = *(const f32x4*)(pwA + quad * 8 + 4);
            r2 = *(const f32x4*)(pwA + 32 + quad * 8); r3 = *(const f32x4*)(pwA + 32 + quad * 8 + 4);
#pragma unroll
            for (int j = 0; j < 4; ++j) { qA0[j]=(_Float16)r0[j]; qA0[4+j]=(_Float16)r1[j];
                                          qA1[j]=(_Float16)r2[j]; qA1[4+j]=(_Float16)r3[j]; }
            r0 = *(const f32x4*)(pwB + quad * 8);      r1 = *(const f32x4*)(pwB + quad * 8 + 4);
            r2 = *(const f32x4*)(pwB + 32 + quad * 8); r3 = *(const f32x4*)(pwB + 32 + quad * 8 + 4);
#pragma unroll
            for (int j = 0; j < 4; ++j) { qB0[j]=(_Float16)r0[j]; qB0[4+j]=(_Float16)r1[j];
                                          qB1[j]=(_Float16)r2[j]; qB1[4+j]=(_Float16)r3[j]; }
        }
        const float mkA = vmask[(pA << 4) + l15];
        const float mkB = vmask[(pB << 4) + l15];
        const float* xgA = xyz + rowA * 3;
        const float* xgB = xyz + rowB * 3;
        const float xgA0 = xgA[0], xgA1 = xgA[1], xgA2 = xgA[2];
        const float xgB0 = xgB[0], xgB1 = xgB[1], xgB2 = xgB[2];
        const float* xsA = xyzs + (size_t)pA * 3;
        const float* xsB = xyzs + (size_t)pB * 3;
        const float xsA0 = xsA[0], xsA1 = xsA[1], xsA2 = xsA[2];
        const float xsB0 = xsB[0], xsB1 = xsB[1], xsB2 = xsB[2];

        // prefetch next iteration's neighbor indices
        const int nbAn = nidx[(pAn << 4) + l15];
        const int nbBn = nidx[((pAn + 1) << 4) + l15];

        if (mkA == 0.0f) { qA0 = (h8)(_Float16)0.f; qA1 = (h8)(_Float16)0.f; }
        if (mkB == 0.0f) { qB0 = (h8)(_Float16)0.f; qB1 = (h8)(_Float16)0.f; }
        h8 aA2 = (h8)(_Float16)0.f, aB2 = (h8)(_Float16)0.f;
        if (quad == 0) {
            aA2[0] = (_Float16)(xgA0 * mkA - xsA0);
            aA2[1] = (_Float16)(xgA1 * mkA - xsA1);
            aA2[2] = (_Float16)(xgA2 * mkA - xsA2);
            aA2[3] = (_Float16)1.0f;               // bias channel
            aB2[0] = (_Float16)(xgB0 * mkB - xsB0);
            aB2[1] = (_Float16)(xgB1 * mkB - xsB1);
            aB2[2] = (_Float16)(xgB2 * mkB - xsB2);
            aB2[3] = (_Float16)1.0f;
        }

        // ---- layer 0 SWAPPED: D = W0'' X^T -> acc[r] = X1[16nt+4q+r][nb=l15]
#pragma unroll
        for (int nt = 0; nt < 4; ++nt) {
            f32x4 aA = {0.f,0.f,0.f,0.f}, aB = {0.f,0.f,0.f,0.f};
            aA = __builtin_amdgcn_mfma_f32_16x16x32_f16(b0f[nt][0], qA0, aA, 0, 0, 0);
            aA = __builtin_amdgcn_mfma_f32_16x16x32_f16(b0f[nt][1], qA1, aA, 0, 0, 0);
            aA = __builtin_amdgcn_mfma_f32_16x16x32_f16(b0f[nt][2], aA2, aA, 0, 0, 0);
            aB = __builtin_amdgcn_mfma_f32_16x16x32_f16(b0f[nt][0], qB0, aB, 0, 0, 0);
            aB = __builtin_amdgcn_mfma_f32_16x16x32_f16(b0f[nt][1], qB1, aB, 0, 0, 0);
            aB = __builtin_amdgcn_mfma_f32_16x16x32_f16(b0f[nt][2], aB2, aB, 0, 0, 0);
            u32x2 pkA = {PK2(aA[0], aA[1]), PK2(aA[2], aA[3])};
            u32x2 pkB = {PK2(aB[0], aB[1]), PK2(aB[2], aB[3])};
            const int cw = (nt * 8 + quad * 2) ^ m;
            *(u32x2*)(XA + l15 * 32 + cw) = pkA;
            *(u32x2*)(XB + l15 * 32 + cw) = pkB;
        }

        // ---- layer 1 SWAPPED (reads precede overwrites; DS in-order/wave) ----
        h8 xA0 = *(const h8*)(XA + l15 * 32 + c0);
        h8 xA1 = *(const h8*)(XA + l15 * 32 + c1);
        h8 xB0 = *(const h8*)(XB + l15 * 32 + c0);
        h8 xB1 = *(const h8*)(XB + l15 * 32 + c1);
#pragma unroll 2
        for (int nt = 0; nt < 4; ++nt) {
            const _Float16* wrow = ldsW1 + (nt * 16 + l15) * 64;
            h8 wa = *(const h8*)(wrow + (c0 << 1));
            h8 wb = *(const h8*)(wrow + (c1 << 1));
            const f32x4 t1 = *(const f32x4*)(t1sh + nt * 16 + quad * 4);
            f32x4 aA = t1, aB = t1;      // bias in accumulator (ch = 16nt+4q+r)
            aA = __builtin_amdgcn_mfma_f32_16x16x32_f16(wa, xA0, aA, 0, 0, 0);
            aA = __builtin_amdgcn_mfma_f32_16x16x32_f16(wb, xA1, aA, 0, 0, 0);
            aB = __builtin_amdgcn_mfma_f32_16x16x32_f16(wa, xB0, aB, 0, 0, 0);
            aB = __builtin_amdgcn_mfma_f32_16x16x32_f16(wb, xB1, aB, 0, 0, 0);
            u32x2 pkA = {PK2(aA[0], aA[1]), PK2(aA[2], aA[3])};
            u32x2 pkB = {PK2(aB[0], aB[1]), PK2(aB[2], aB[3])};
            const int cw = (nt * 8 + quad * 2) ^ m;
            *(u32x2*)(XA + l15 * 32 + cw) = pkA;
            *(u32x2*)(XB + l15 * 32 + cw) = pkB;
        }

        // ---- layer 2 NORMAL: X frags as A-operand + K-maxpool + packed stores
        h8 yA0 = *(const h8*)(XA + l15 * 32 + c0);
        h8 yA1 = *(const h8*)(XA + l15 * 32 + c1);
        h8 yB0 = *(const h8*)(XB + l15 * 32 + c0);
        h8 yB1 = *(const h8*)(XB + l15 * 32 + c1);
        float sAlo = 0.f, sAhi = 0.f, sBlo = 0.f, sBhi = 0.f;
#pragma unroll 2
        for (int nt = 0; nt < 8; ++nt) {
            const _Float16* wrow = ldsW2 + (nt * 16 + l15) * 64;
            h8 wa = *(const h8*)(wrow + (c0 << 1));
            h8 wb = *(const h8*)(wrow + (c1 << 1));
            const float t2 = t2sh[nt * 16 + l15];
            f32x4 aA = {0.f,0.f,0.f,0.f}, aB = {0.f,0.f,0.f,0.f};
            aA = __builtin_amdgcn_mfma_f32_16x16x32_f16(yA0, wa, aA, 0, 0, 0);
            aA = __builtin_amdgcn_mfma_f32_16x16x32_f16(yA1, wb, aA, 0, 0, 0);
            aB = __builtin_amdgcn_mfma_f32_16x16x32_f16(yB0, wa, aB, 0, 0, 0);
            aB = __builtin_amdgcn_mfma_f32_16x16x32_f16(yB1, wb, aB, 0, 0, 0);
            float vA = fmaxf(fmaxf(aA[0], aA[1]), fmaxf(aA[2], aA[3])) + t2;
            float vB = fmaxf(fmaxf(aB[0], aB[1]), fmaxf(aB[2], aB[3])) + t2;
            vA = fmaxf(vA, 0.f);  vB = fmaxf(vB, 0.f);    // relu(max)=max(relu)
            vA = fmaxf(vA, __shfl_xor(vA, 16, 64));
            vA = fmaxf(vA, __shfl_xor(vA, 32, 64));       // now quad-uniform
            vB = fmaxf(vB, __shfl_xor(vB, 16, 64));
            vB = fmaxf(vB, __shfl_xor(vB, 32, 64));
            // select this lane's channel (ch = quad*16+l15 or +64):
            if (nt < 4) {
                sAlo = (quad == nt) ? vA : sAlo;
                sBlo = (quad == nt) ? vB : sBlo;
            } else {
                sAhi = (quad == nt - 4) ? vA : sAhi;
                sBhi = (quad == nt - 4) ? vB : sBhi;
            }
        }
        // all 64 lanes store; lane = quad*16+l15 -> 256B coalesced stores
        {
            float* obA = out + ((size_t)pA << 7);
            float* obB = out + ((size_t)pB << 7);
            obA[lane]                  = sAlo;
            obA[64 + lane]             = sAhi;
            obA[OUTHALF_ + lane]       = sAlo;
            obA[OUTHALF_ + 64 + lane]  = sAhi;
            obB[lane]                  = sBlo;
            obB[64 + lane]             = sBhi;
            obB[OUTHALF_ + lane]       = sBlo;
            obB[OUTHALF_ + 64 + lane]  = sBhi;
        }

        nbA = nbAn; nbB = nbBn;
    }
}

extern "C" void kernel_launch(void* const* d_in, const int* in_sizes, int n_in,
                              void* d_out, int out_size, void* d_ws, size_t ws_size,
                              hipStream_t stream) {
    const float* xyz   = (const float*)d_in[0];
    const float* pts   = (const float*)d_in[1];
    const float* xyzs  = (const float*)d_in[2];
    const int*   nidx  = (const int*)d_in[3];
    const float* vmask = (const float*)d_in[4];
    const float *w0 = (const float*)d_in[5],  *b0 = (const float*)d_in[6],
                *g0 = (const float*)d_in[7],  *be0 = (const float*)d_in[8],
                *m0 = (const float*)d_in[9],  *v0 = (const float*)d_in[10];
    const float *w1 = (const float*)d_in[11], *b1 = (const float*)d_in[12],
                *g1 = (const float*)d_in[13], *be1 = (const float*)d_in[14],
                *m1 = (const float*)d_in[15], *v1 = (const float*)d_in[16];
    const float *w2 = (const float*)d_in[17], *b2 = (const float*)d_in[18],
                *g2 = (const float*)d_in[19], *be2 = (const float*)d_in[20],
                *m2 = (const float*)d_in[21], *v2 = (const float*)d_in[22];
    float* outp = (float*)d_out;

    pnsa_main<<<dim3(GRID_), dim3(256), 0, stream>>>(
        xyz, pts, xyzs, nidx, vmask,
        w0, b0, g0, be0, m0, v0,
        w1, b1, g1, be1, m1, v1,
        w2, b2, g2, be2, m2, v2, outp);
}

// Round 13
// 213.665 us; speedup vs baseline: 1.3545x; 1.0006x over previous
//
#include <hip/hip_runtime.h>

// PointNetSaModule fused — f32 in/out, f16 MFMA compute.
// R19 = R18 with the compile error fixed (R18 never ran):
//   - cvt_pkrtz returns __fp16x2, and ext_vector elements have no address.
//     Fix: bit_cast pkrtz result to unsigned, assemble frag as u32x4 ->
//     bit_cast to h8 (same pattern as the validated PK2 path).
// Experiment unchanged from R18:
//   1) s_setprio(1) around MFMA clusters (T5; barrier-free independent-wave
//      loop = the favorable regime; null on lockstep kernels).
//   2) packed gather convert: 32 -> 16 cvt per point (-32 VALU/wave-iter).
// Base = R17 (main 88.2us, headline 213.8): swizzled unpadded LDS, PK2
// activations, f32 direct gather, packed stores, (256,3)/768.
// If setprio nulls, declare floor: ~123us fixed overhead + ~88us
// latency-bound kernel at the fully-probed register/LDS frontier.

#define NGRP_    8192         // groups of 8 points (B*h*w/8)
#define OUTHALF_ 8388608      // elements: second output copy offset
#define EPS_     1e-5f
#define GRID_    768          // 3 blocks/CU x 256 CUs

typedef _Float16 h8    __attribute__((ext_vector_type(8)));
typedef float    f32x4 __attribute__((ext_vector_type(4)));
typedef unsigned u32x2 __attribute__((ext_vector_type(2)));
typedef unsigned u32x4 __attribute__((ext_vector_type(4)));

// relu + pack two f32 -> one u32 of 2 f16 (single v_cvt_pkrtz_f16_f32)
#define PK2(lo, hi) __builtin_bit_cast(unsigned,                               \
    __builtin_amdgcn_cvt_pkrtz(fmaxf((lo), 0.f), fmaxf((hi), 0.f)))

// pack two f32 -> one u32 of 2 f16 (no relu) for the gather convert
#define CV(lo, hi) __builtin_bit_cast(unsigned,                                \
    __builtin_amdgcn_cvt_pkrtz((lo), (hi)))

__global__ __launch_bounds__(256, 3) void pnsa_main(
    const float* __restrict__ xyz,    // (B,HW,3) f32
    const float* __restrict__ pts,    // (B,HW,64) f32
    const float* __restrict__ xyzs,   // (B,NPT,3) f32
    const int*   __restrict__ nidx,   // (B,NPT*16)
    const float* __restrict__ vmask,  // (B,NPT,16) f32
    const float* __restrict__ w0, const float* __restrict__ b0,
    const float* __restrict__ g0, const float* __restrict__ be0,
    const float* __restrict__ m0, const float* __restrict__ v0,
    const float* __restrict__ w1, const float* __restrict__ b1,
    const float* __restrict__ g1, const float* __restrict__ be1,
    const float* __restrict__ m1, const float* __restrict__ v1,
    const float* __restrict__ w2, const float* __restrict__ b2,
    const float* __restrict__ g2, const float* __restrict__ be2,
    const float* __restrict__ m2, const float* __restrict__ v2,
    float*       __restrict__ out)
{
    // LDS: 8192 + 16384 + 16384 + 512 + 1024 = 42,496B -> 3 blocks/CU
    __shared__ __align__(16) _Float16 ldsW1[64 * 64];        // W1'[n][k swz]
    __shared__ __align__(16) _Float16 ldsW2[128 * 64];       // W2'[n][k swz]
    __shared__ __align__(16) unsigned ldsX[4][2][16 * 32];   // X'[nb][ch/2 swz]
    __shared__ __align__(16) float    s1sh[64], t1sh[64];
    __shared__ __align__(16) float    s2sh[128], t2sh[128];

    const int tid  = threadIdx.x;
    const int wave = tid >> 6;
    const int lane = tid & 63;
    const int l15  = lane & 15;
    const int quad = lane >> 4;
    const int m    = (l15 & 7) << 2;          // XOR swizzle mask (u32 units)
    const int c0   = (quad * 4) ^ m;          // swizzled u32 col, k-chunk 0
    const int c1   = (16 + quad * 4) ^ m;     // swizzled u32 col, k-chunk 1

    unsigned* XA = &ldsX[wave][0][0];
    unsigned* XB = &ldsX[wave][1][0];

    // ---- stage BN scales + shifted biases ----
    if (tid < 64) {
        const float s = g1[tid] * rsqrtf(v1[tid] + EPS_);
        s1sh[tid] = s;
        t1sh[tid] = (b1[tid] - m1[tid]) * s + be1[tid];
    }
    if (tid < 128) {
        const float s = g2[tid] * rsqrtf(v2[tid] + EPS_);
        s2sh[tid] = s;
        t2sh[tid] = (b2[tid] - m2[tid]) * s + be2[tid];
    }
    __syncthreads();
    // ---- fold W1'/W2' into swizzled LDS ----
    for (int idx = tid; idx < 64 * 64; idx += 256) {     // w1[k][n] -> W1'[n][k]
        const int k = idx >> 6, n = idx & 63;
        const int c = (k >> 1) ^ ((n & 7) << 2);
        ldsW1[n * 64 + (c << 1) + (k & 1)] = (_Float16)(w1[idx] * s1sh[n]);
    }
    for (int idx = tid; idx < 64 * 128; idx += 256) {    // w2[k][n] -> W2'[n][k]
        const int k = idx >> 7, n = idx & 127;
        const int c = (k >> 1) ^ ((n & 7) << 2);
        ldsW2[n * 64 + (c << 1) + (k & 1)] = (_Float16)(w2[idx] * s2sh[n]);
    }
    __syncthreads();

    // ---- W0 BN-folded into register frags; bias via pad channel 67 ----
    // k-order: [points 0..63, xyz_diff 64..66, BIAS 67 (=1.0), pad..95]
    // Frag map (A==B on gfx950): lane holds [ch=nt*16+l15][k=kk*32+quad*8+j]
    h8 b0f[4][3];
#pragma unroll
    for (int nt = 0; nt < 4; ++nt) {
        const int ch = nt * 16 + l15;
        const float s = g0[ch] * rsqrtf(v0[ch] + EPS_);
        const float t0 = (b0[ch] - m0[ch]) * s + be0[ch];
#pragma unroll
        for (int kk = 0; kk < 3; ++kk) {
            h8 f;
#pragma unroll
            for (int j = 0; j < 8; ++j) {
                const int k = kk * 32 + quad * 8 + j;
                float wv = 0.f;
                if (k < 64)       wv = w0[(3 + k) * 64 + ch] * s;
                else if (k < 67)  wv = w0[(k - 64) * 64 + ch] * s;
                else if (k == 67) wv = t0;                 // bias via 1.0 channel
                f[j] = (_Float16)wv;
            }
            b0f[nt][kk] = f;
        }
    }

    // ---- main loop: 8 points per block iteration (2 per wave) ----
    const int g0i = blockIdx.x;
    const int pA0 = (g0i << 3) + (wave << 1);
    int nbA = nidx[(pA0 << 4) + l15];
    int nbB = nidx[((pA0 + 1) << 4) + l15];

    for (int grp = g0i; grp < NGRP_; grp += GRID_) {
        const int pA = (grp << 3) + (wave << 1);
        const int pB = pA + 1;
        const int gn = (grp + GRID_ < NGRP_) ? grp + GRID_ : grp;
        const int pAn = (gn << 3) + (wave << 1);

        // gather loads for both points (issue early), f32 direct;
        // packed f32->f16 convert via cvt_pkrtz (u32 words -> h8 bit_cast)
        const size_t rowA = (size_t)(((pA >> 14) << 16) + nbA);
        const size_t rowB = (size_t)(((pB >> 14) << 16) + nbB);
        h8 qA0, qA1, qB0, qB1;
        {
            const float* pwA = pts + (rowA << 6);
            const float* pwB = pts + (rowB << 6);
            f32x4 r0, r1, r2, r3;
            r0 = *(const f32x4*)(pwA + quad * 8);      r1 = *(const f32x4*)(pwA + quad * 8 + 4);
            r2 = *(const f32x4*)(pwA + 32 + quad * 8); r3 = *(const f32x4*)(pwA + 32 + quad * 8 + 4);
            {
                u32x4 u0 = {CV(r0[0], r0[1]), CV(r0[2], r0[3]),
                            CV(r1[0], r1[1]), CV(r1[2], r1[3])};
                u32x4 u1 = {CV(r2[0], r2[1]), CV(r2[2], r2[3]),
                            CV(r3[0], r3[1]), CV(r3[2], r3[3])};
                qA0 = __builtin_bit_cast(h8, u0);
                qA1 = __builtin_bit_cast(h8, u1);
            }
            r0 = *(const f32x4*)(pwB + quad * 8);      r1 = *(const f32x4*)(pwB + quad * 8 + 4);
            r2 = *(const f32x4*)(pwB + 32 + quad * 8); r3 = *(const f32x4*)(pwB + 32 + quad * 8 + 4);
            {
                u32x4 u0 = {CV(r0[0], r0[1]), CV(r0[2], r0[3]),
                            CV(r1[0], r1[1]), CV(r1[2], r1[3])};
                u32x4 u1 = {CV(r2[0], r2[1]), CV(r2[2], r2[3]),
                            CV(r3[0], r3[1]), CV(r3[2], r3[3])};
                qB0 = __builtin_bit_cast(h8, u0);
                qB1 = __builtin_bit_cast(h8, u1);
            }
        }
        const float mkA = vmask[(pA << 4) + l15];
        const float mkB = vmask[(pB << 4) + l15];
        const float* xgA = xyz + rowA * 3;
        const float* xgB = xyz + rowB * 3;
        const float xgA0 = xgA[0], xgA1 = xgA[1], xgA2 = xgA[2];
        const float xgB0 = xgB[0], xgB1 = xgB[1], xgB2 = xgB[2];
        const float* xsA = xyzs + (size_t)pA * 3;
        const float* xsB = xyzs + (size_t)pB * 3;
        const float xsA0 = xsA[0], xsA1 = xsA[1], xsA2 = xsA[2];
        const float xsB0 = xsB[0], xsB1 = xsB[1], xsB2 = xsB[2];

        // prefetch next iteration's neighbor indices
        const int nbAn = nidx[(pAn << 4) + l15];
        const int nbBn = nidx[((pAn + 1) << 4) + l15];

        if (mkA == 0.0f) { qA0 = (h8)(_Float16)0.f; qA1 = (h8)(_Float16)0.f; }
        if (mkB == 0.0f) { qB0 = (h8)(_Float16)0.f; qB1 = (h8)(_Float16)0.f; }
        h8 aA2 = (h8)(_Float16)0.f, aB2 = (h8)(_Float16)0.f;
        if (quad == 0) {
            aA2[0] = (_Float16)(xgA0 * mkA - xsA0);
            aA2[1] = (_Float16)(xgA1 * mkA - xsA1);
            aA2[2] = (_Float16)(xgA2 * mkA - xsA2);
            aA2[3] = (_Float16)1.0f;               // bias channel
            aB2[0] = (_Float16)(xgB0 * mkB - xsB0);
            aB2[1] = (_Float16)(xgB1 * mkB - xsB1);
            aB2[2] = (_Float16)(xgB2 * mkB - xsB2);
            aB2[3] = (_Float16)1.0f;
        }

        // ---- layer 0 SWAPPED: D = W0'' X^T -> acc[r] = X1[16nt+4q+r][nb=l15]
        __builtin_amdgcn_s_setprio(1);
#pragma unroll
        for (int nt = 0; nt < 4; ++nt) {
            f32x4 aA = {0.f,0.f,0.f,0.f}, aB = {0.f,0.f,0.f,0.f};
            aA = __builtin_amdgcn_mfma_f32_16x16x32_f16(b0f[nt][0], qA0, aA, 0, 0, 0);
            aA = __builtin_amdgcn_mfma_f32_16x16x32_f16(b0f[nt][1], qA1, aA, 0, 0, 0);
            aA = __builtin_amdgcn_mfma_f32_16x16x32_f16(b0f[nt][2], aA2, aA, 0, 0, 0);
            aB = __builtin_amdgcn_mfma_f32_16x16x32_f16(b0f[nt][0], qB0, aB, 0, 0, 0);
            aB = __builtin_amdgcn_mfma_f32_16x16x32_f16(b0f[nt][1], qB1, aB, 0, 0, 0);
            aB = __builtin_amdgcn_mfma_f32_16x16x32_f16(b0f[nt][2], aB2, aB, 0, 0, 0);
            u32x2 pkA = {PK2(aA[0], aA[1]), PK2(aA[2], aA[3])};
            u32x2 pkB = {PK2(aB[0], aB[1]), PK2(aB[2], aB[3])};
            const int cw = (nt * 8 + quad * 2) ^ m;
            *(u32x2*)(XA + l15 * 32 + cw) = pkA;
            *(u32x2*)(XB + l15 * 32 + cw) = pkB;
        }
        __builtin_amdgcn_s_setprio(0);

        // ---- layer 1 SWAPPED (reads precede overwrites; DS in-order/wave) ----
        h8 xA0 = *(const h8*)(XA + l15 * 32 + c0);
        h8 xA1 = *(const h8*)(XA + l15 * 32 + c1);
        h8 xB0 = *(const h8*)(XB + l15 * 32 + c0);
        h8 xB1 = *(const h8*)(XB + l15 * 32 + c1);
        __builtin_amdgcn_s_setprio(1);
#pragma unroll 2
        for (int nt = 0; nt < 4; ++nt) {
            const _Float16* wrow = ldsW1 + (nt * 16 + l15) * 64;
            h8 wa = *(const h8*)(wrow + (c0 << 1));
            h8 wb = *(const h8*)(wrow + (c1 << 1));
            const f32x4 t1 = *(const f32x4*)(t1sh + nt * 16 + quad * 4);
            f32x4 aA = t1, aB = t1;      // bias in accumulator (ch = 16nt+4q+r)
            aA = __builtin_amdgcn_mfma_f32_16x16x32_f16(wa, xA0, aA, 0, 0, 0);
            aA = __builtin_amdgcn_mfma_f32_16x16x32_f16(wb, xA1, aA, 0, 0, 0);
            aB = __builtin_amdgcn_mfma_f32_16x16x32_f16(wa, xB0, aB, 0, 0, 0);
            aB = __builtin_amdgcn_mfma_f32_16x16x32_f16(wb, xB1, aB, 0, 0, 0);
            u32x2 pkA = {PK2(aA[0], aA[1]), PK2(aA[2], aA[3])};
            u32x2 pkB = {PK2(aB[0], aB[1]), PK2(aB[2], aB[3])};
            const int cw = (nt * 8 + quad * 2) ^ m;
            *(u32x2*)(XA + l15 * 32 + cw) = pkA;
            *(u32x2*)(XB + l15 * 32 + cw) = pkB;
        }
        __builtin_amdgcn_s_setprio(0);

        // ---- layer 2 NORMAL: X frags as A-operand + K-maxpool + packed stores
        h8 yA0 = *(const h8*)(XA + l15 * 32 + c0);
        h8 yA1 = *(const h8*)(XA + l15 * 32 + c1);
        h8 yB0 = *(const h8*)(XB + l15 * 32 + c0);
        h8 yB1 = *(const h8*)(XB + l15 * 32 + c1);
        float sAlo = 0.f, sAhi = 0.f, sBlo = 0.f, sBhi = 0.f;
#pragma unroll 2
        for (int nt = 0; nt < 8; ++nt) {
            const _Float16* wrow = ldsW2 + (nt * 16 + l15) * 64;
            h8 wa = *(const h8*)(wrow + (c0 << 1));
            h8 wb = *(const h8*)(wrow + (c1 << 1));
            const float t2 = t2sh[nt * 16 + l15];
            __builtin_amdgcn_s_setprio(1);
            f32x4 aA = {0.f,0.f,0.f,0.f}, aB = {0.f,0.f,0.f,0.f};
            aA = __builtin_amdgcn_mfma_f32_16x16x32_f16(yA0, wa, aA, 0, 0, 0);
            aA = __builtin_amdgcn_mfma_f32_16x16x32_f16(yA1, wb, aA, 0, 0, 0);
            aB = __builtin_amdgcn_mfma_f32_16x16x32_f16(yB0, wa, aB, 0, 0, 0);
            aB = __builtin_amdgcn_mfma_f32_16x16x32_f16(yB1, wb, aB, 0, 0, 0);
            __builtin_amdgcn_s_setprio(0);
            float vA = fmaxf(fmaxf(aA[0], aA[1]), fmaxf(aA[2], aA[3])) + t2;
            float vB = fmaxf(fmaxf(aB[0], aB[1]), fmaxf(aB[2], aB[3])) + t2;
            vA = fmaxf(vA, 0.f);  vB = fmaxf(vB, 0.f);    // relu(max)=max(relu)
            vA = fmaxf(vA, __shfl_xor(vA, 16, 64));
            vA = fmaxf(vA, __shfl_xor(vA, 32, 64));       // now quad-uniform
            vB = fmaxf(vB, __shfl_xor(vB, 16, 64));
            vB = fmaxf(vB, __shfl_xor(vB, 32, 64));
            // select this lane's channel (ch = quad*16+l15 or +64):
            if (nt < 4) {
                sAlo = (quad == nt) ? vA : sAlo;
                sBlo = (quad == nt) ? vB : sBlo;
            } else {
                sAhi = (quad == nt - 4) ? vA : sAhi;
                sBhi = (quad == nt - 4) ? vB : sBhi;
            }
        }
        // all 64 lanes store; lane = quad*16+l15 -> 256B coalesced stores
        {
            float* obA = out + ((size_t)pA << 7);
            float* obB = out + ((size_t)pB << 7);
            obA[lane]                  = sAlo;
            obA[64 + lane]             = sAhi;
            obA[OUTHALF_ + lane]       = sAlo;
            obA[OUTHALF_ + 64 + lane]  = sAhi;
            obB[lane]                  = sBlo;
            obB[64 + lane]             = sBhi;
            obB[OUTHALF_ + lane]       = sBlo;
            obB[OUTHALF_ + 64 + lane]  = sBhi;
        }

        nbA = nbAn; nbB = nbBn;
    }
}

extern "C" void kernel_launch(void* const* d_in, const int* in_sizes, int n_in,
                              void* d_out, int out_size, void* d_ws, size_t ws_size,
                              hipStream_t stream) {
    const float* xyz   = (const float*)d_in[0];
    const float* pts   = (const float*)d_in[1];
    const float* xyzs  = (const float*)d_in[2];
    const int*   nidx  = (const int*)d_in[3];
    const float* vmask = (const float*)d_in[4];
    const float *w0 = (const float*)d_in[5],  *b0 = (const float*)d_in[6],
                *g0 = (const float*)d_in[7],  *be0 = (const float*)d_in[8],
                *m0 = (const float*)d_in[9],  *v0 = (const float*)d_in[10];
    const float *w1 = (const float*)d_in[11], *b1 = (const float*)d_in[12],
                *g1 = (const float*)d_in[13], *be1 = (const float*)d_in[14],
                *m1 = (const float*)d_in[15], *v1 = (const float*)d_in[16];
    const float *w2 = (const float*)d_in[17], *b2 = (const float*)d_in[18],
                *g2 = (const float*)d_in[19], *be2 = (const float*)d_in[20],
                *m2 = (const float*)d_in[21], *v2 = (const float*)d_in[22];
    float* outp = (float*)d_out;

    pnsa_main<<<dim3(GRID_), dim3(256), 0, stream>>>(
        xyz, pts, xyzs, nidx, vmask,
        w0, b0, g0, be0, m0, v0,
        w1, b1, g1, be1, m1, v1,
        w2, b2, g2, be2, m2, v2, outp);
}